// Round 3
// baseline (2522.940 us; speedup 1.0000x reference)
//
#include <hip/hip_runtime.h>
#include <hip/hip_bf16.h>

#define N_NODES 100000
#define N_EDGES 1600000
#define IN_DIM 8
#define D 50
#define D2 100
#define NTASK 112
#define BN_EPS 1e-5f
#define NBLK ((N_NODES + 255) / 256)   // 391 scan blocks

// ---------------------------------------------------------------------------
// node encoder: h[n,j] = nf[n,:] @ nW + nb   (h row stride = hs)
// ---------------------------------------------------------------------------
#define NE_NODES 40
__global__ __launch_bounds__(256) void node_enc_kernel(
    const float* __restrict__ nf, const float* __restrict__ nW,
    const float* __restrict__ nb, float* __restrict__ h, int hs) {
    __shared__ float sW[IN_DIM * D];
    __shared__ float sb[D];
    __shared__ float snf[NE_NODES * IN_DIM];
    int t = threadIdx.x;
    int n0 = blockIdx.x * NE_NODES;
    for (int i = t; i < IN_DIM * D; i += 256) sW[i] = nW[i];
    for (int i = t; i < D; i += 256) sb[i] = nb[i];
    for (int i = t; i < NE_NODES * IN_DIM; i += 256) {
        int g = n0 * IN_DIM + i;
        snf[i] = (g < N_NODES * IN_DIM) ? nf[g] : 0.0f;
    }
    __syncthreads();
    int j = t % D, grp = t / D;
    if (grp < 5) {
        for (int n = grp * 8; n < grp * 8 + 8; n++) {
            int g = n0 + n;
            if (g >= N_NODES) break;
            float v = sb[j];
#pragma unroll
            for (int k = 0; k < IN_DIM; k++) v += snf[n * IN_DIM + k] * sW[k * D + j];
            h[(size_t)g * hs + j] = v;
        }
    }
}

// ---------------------------------------------------------------------------
// CSR build
// ---------------------------------------------------------------------------
__global__ void k_deg(const int* __restrict__ dst, int* __restrict__ degi) {
    int e = blockIdx.x * blockDim.x + threadIdx.x;
    if (e < N_EDGES) atomicAdd(&degi[dst[e]], 1);
}

__global__ void k_bsum(const int* __restrict__ degi, int* __restrict__ bsum) {
    __shared__ int lds[256];
    int t = threadIdx.x, i = blockIdx.x * 256 + t;
    lds[t] = (i < N_NODES) ? degi[i] : 0;
    __syncthreads();
    for (int s = 128; s > 0; s >>= 1) {
        if (t < s) lds[t] += lds[t + s];
        __syncthreads();
    }
    if (t == 0) bsum[blockIdx.x] = lds[0];
}

__global__ void k_bscan(const int* __restrict__ bsum, int* __restrict__ bpre) {
    __shared__ int lds[512];
    int t = threadIdx.x;
    int x = (t < NBLK) ? bsum[t] : 0;
    lds[t] = x;
    __syncthreads();
    int acc = x;
    for (int s = 1; s < 512; s <<= 1) {
        int add = (t >= s) ? lds[t - s] : 0;
        __syncthreads();
        acc += add;
        lds[t] = acc;
        __syncthreads();
    }
    if (t < NBLK) bpre[t] = acc - x;
}

__global__ void k_off(const int* __restrict__ degi, const int* __restrict__ bpre,
                      int* __restrict__ off, int* __restrict__ cursor,
                      float* __restrict__ invd) {
    __shared__ int lds[256];
    int t = threadIdx.x, i = blockIdx.x * 256 + t;
    int dv = (i < N_NODES) ? degi[i] : 0;
    lds[t] = dv;
    __syncthreads();
    int acc = dv;
    for (int s = 1; s < 256; s <<= 1) {
        int add = (t >= s) ? lds[t - s] : 0;
        __syncthreads();
        acc += add;
        lds[t] = acc;
        __syncthreads();
    }
    int excl = acc - dv + bpre[blockIdx.x];
    if (i < N_NODES) {
        off[i] = excl;
        cursor[i] = excl;
        invd[i] = (dv > 0) ? (1.0f / (float)dv) : 0.0f;
    }
    if (i == 0) off[N_NODES] = N_EDGES;
}

__global__ void k_fill(const int* __restrict__ src, const int* __restrict__ dst,
                       int* __restrict__ cursor, int* __restrict__ adjs,
                       int* __restrict__ adje) {
    int e = blockIdx.x * blockDim.x + threadIdx.x;
    if (e >= N_EDGES) return;
    int d = dst[e];
    int pos = atomicAdd(&cursor[d], 1);
    adjs[pos] = src[e];
    adje[pos] = e;
}

// ---------------------------------------------------------------------------
// aggef[n,k] = sum over incoming edges of ef[e,k]   (once per call)
// wave per node; lane = (edge-in-group g = lane>>3, component k = lane&7)
// ---------------------------------------------------------------------------
__global__ __launch_bounds__(256) void k_aggef(
    const int* __restrict__ off, const int* __restrict__ adje,
    const float* __restrict__ ef, float* __restrict__ aggef) {
    int lane = threadIdx.x & 63, wv = threadIdx.x >> 6;
    int n = blockIdx.x * 4 + wv;
    if (n >= N_NODES) return;
    int p0 = off[n], pend = off[n + 1];
    int g = lane >> 3, k = lane & 7;
    float a = 0.0f;
    for (int q = p0 + g; q < pend; q += 8) {
        int e = adje[q];
        a += ef[(size_t)e * 8 + k];
    }
    a += __shfl_xor(a, 8, 64);
    a += __shfl_xor(a, 16, 64);
    a += __shfl_xor(a, 32, 64);
    if (lane < 8) aggef[(size_t)n * 8 + lane] = a;
}

// ---------------------------------------------------------------------------
// gather + eps-combine. FULL mode (use_ebase): pure h[src] gather, edge-enc
// contribution folded in per-node via aggef @ eW. LEAN mode: R2-style.
// ---------------------------------------------------------------------------
__global__ __launch_bounds__(256) void gather_kernel(
    const int* __restrict__ off, const int* __restrict__ adjs,
    const int* __restrict__ adje, const float* __restrict__ aggef,
    const float* __restrict__ ef, const float* __restrict__ eW,
    const float* __restrict__ eb, const float* __restrict__ h, int hs,
    const float* __restrict__ invd, const float* __restrict__ epsArr, int layer,
    float* __restrict__ hnew, int use_ebase) {
    __shared__ float sW[IN_DIM * D];
    __shared__ float sB[D];
    int t = threadIdx.x;
    for (int i = t; i < IN_DIM * D; i += 256) sW[i] = eW[i];
    for (int i = t; i < D; i += 256) sB[i] = eb[i];
    __syncthreads();
    int lane = t & 63, wv = t >> 6;
    int n = blockIdx.x * 4 + wv;
    if (n >= N_NODES) return;
    int dd = (lane < D) ? lane : (D - 1);
    int p = off[n], pend = off[n + 1];
    int deg = pend - p;
    float acc = 0.0f;
    if (use_ebase) {
        while (p + 4 <= pend) {
            int s0 = adjs[p], s1 = adjs[p + 1], s2 = adjs[p + 2], s3 = adjs[p + 3];
            float h0 = h[(size_t)s0 * hs + dd];
            float h1 = h[(size_t)s1 * hs + dd];
            float h2 = h[(size_t)s2 * hs + dd];
            float h3 = h[(size_t)s3 * hs + dd];
            acc += h0 + h1 + h2 + h3;
            p += 4;
        }
        while (p < pend) { acc += h[(size_t)adjs[p] * hs + dd]; p++; }
    } else {
        const float4* ef4 = (const float4*)ef;
        while (p < pend) {
            int s = adjs[p], e = adje[p];
            float hv = h[(size_t)s * hs + dd];
            float4 f0 = ef4[(size_t)e * 2];
            float4 f1 = ef4[(size_t)e * 2 + 1];
            float ev = sB[dd];
            ev += f0.x * sW[0 * D + dd];
            ev += f0.y * sW[1 * D + dd];
            ev += f0.z * sW[2 * D + dd];
            ev += f0.w * sW[3 * D + dd];
            ev += f1.x * sW[4 * D + dd];
            ev += f1.y * sW[5 * D + dd];
            ev += f1.z * sW[6 * D + dd];
            ev += f1.w * sW[7 * D + dd];
            acc += hv + ev;
            p++;
        }
    }
    if (lane < D) {
        float iv = invd[n];
        float extra = 0.0f;
        if (use_ebase) {
            if (deg > 0) {
                const float* ag = &aggef[(size_t)n * 8];
                float s = 0.0f;
#pragma unroll
                for (int k = 0; k < 8; k++) s += ag[k] * sW[k * D + dd];
                extra = s * iv + sB[dd];
            }
        }
        float epsv = 1.0f + epsArr[layer];
        hnew[(size_t)n * D + lane] = epsv * h[(size_t)n * hs + lane] + iv * acc + extra;
    }
}

// ---------------------------------------------------------------------------
// register-tiled GEMM: Y[N,J] = act(X[N,K]) @ W[K,J] + bias
// 4n x 4j per thread, b128 LDS reads, grid-stride over NB-node tiles.
// Optional BN+ReLU applied to X on load; optional per-column BN stats.
// ---------------------------------------------------------------------------
template<int K, int KP, int J, int JG, int NB, bool BN_IN, bool STATS>
__global__ __launch_bounds__(256) void gemm_tiled(
    const float* __restrict__ X, const float* __restrict__ W,
    const float* __restrict__ bias,
    const float* __restrict__ bna, const float* __restrict__ bnc,
    float* __restrict__ Y, float* __restrict__ sg, float* __restrict__ qg,
    int ntiles) {
    constexpr int JR = JG * 4;
    __shared__ __align__(16) float sh[NB * KP];
    __shared__ __align__(16) float sWT[JR * KP];
    __shared__ float sb[JR];
    __shared__ float sa[K], sc[K];
    __shared__ float sp[J], qp[J];
    int t = threadIdx.x;
    for (int i = t; i < JR * KP; i += 256) {
        int j = i / KP, d = i % KP;
        sWT[i] = (j < J && d < K) ? W[d * J + j] : 0.0f;
    }
    for (int i = t; i < JR; i += 256) sb[i] = (i < J) ? bias[i] : 0.0f;
    if (BN_IN) {
        for (int i = t; i < K; i += 256) { sa[i] = bna[i]; sc[i] = bnc[i]; }
    }
    if (STATS) {
        for (int i = t; i < J; i += 256) { sp[i] = 0.0f; qp[i] = 0.0f; }
    }
    int jg = t % JG, ng = t / JG;
    bool active = (ng < NB / 4);
    float sacc[4] = {0, 0, 0, 0}, qacc[4] = {0, 0, 0, 0};
    for (int tile = blockIdx.x; tile < ntiles; tile += gridDim.x) {
        __syncthreads();   // protect sh reuse across tiles (and first-use after W stage)
        int base = tile * NB;
        for (int i = t; i < NB * KP; i += 256) {
            int n = i / KP, dp = i % KP;
            float v = 0.0f;
            int gn = base + n;
            if (dp < K && gn < N_NODES) {
                v = X[(size_t)gn * K + dp];
                if (BN_IN) v = fmaxf(v * sa[dp] + sc[dp], 0.0f);
            }
            sh[i] = v;
        }
        __syncthreads();
        if (active) {
            int nn0 = ng * 4;
            float acc[4][4];
#pragma unroll
            for (int i = 0; i < 4; i++)
#pragma unroll
                for (int jj = 0; jj < 4; jj++) acc[i][jj] = sb[jg + jj * JG];
#pragma unroll
            for (int d4 = 0; d4 < KP / 4; d4++) {
                float4 av[4], bv[4];
#pragma unroll
                for (int i = 0; i < 4; i++)
                    av[i] = *(const float4*)&sh[(nn0 + i) * KP + d4 * 4];
#pragma unroll
                for (int jj = 0; jj < 4; jj++)
                    bv[jj] = *(const float4*)&sWT[(jg + jj * JG) * KP + d4 * 4];
#pragma unroll
                for (int i = 0; i < 4; i++)
#pragma unroll
                    for (int jj = 0; jj < 4; jj++) {
                        acc[i][jj] += av[i].x * bv[jj].x;
                        acc[i][jj] += av[i].y * bv[jj].y;
                        acc[i][jj] += av[i].z * bv[jj].z;
                        acc[i][jj] += av[i].w * bv[jj].w;
                    }
            }
#pragma unroll
            for (int i = 0; i < 4; i++) {
                int gn = base + nn0 + i;
                if (gn < N_NODES) {
#pragma unroll
                    for (int jj = 0; jj < 4; jj++) {
                        int j = jg + jj * JG;
                        if (j < J) {
                            float v = acc[i][jj];
                            Y[(size_t)gn * J + j] = v;
                            if (STATS) { sacc[jj] += v; qacc[jj] += v * v; }
                        }
                    }
                }
            }
        }
    }
    if (STATS) {
        __syncthreads();
        if (active) {
#pragma unroll
            for (int jj = 0; jj < 4; jj++) {
                int j = jg + jj * JG;
                if (j < J) {
                    atomicAdd(&sp[j], sacc[jj]);
                    atomicAdd(&qp[j], qacc[jj]);
                }
            }
        }
        __syncthreads();
        for (int i = t; i < J; i += 256) {
            atomicAdd(&sg[i], sp[i]);
            atomicAdd(&qg[i], qp[i]);
        }
    }
}

// a = gamma*rsqrt(var+eps); c = beta - mu*a
__global__ void bn_fin_kernel(const float* __restrict__ s, const float* __restrict__ q,
                              const float* __restrict__ gamma, const float* __restrict__ beta,
                              float* __restrict__ a, float* __restrict__ c, int dim) {
    int j = threadIdx.x;
    if (j >= dim) return;
    float inv_n = 1.0f / (float)N_NODES;
    float mu = s[j] * inv_n;
    float var = q[j] * inv_n - mu * mu;
    float rs = rsqrtf(var + BN_EPS);
    float av = gamma[j] * rs;
    a[j] = av;
    c[j] = beta[j] - mu * av;
}

// h = relu(y2*a2+c2)  (h row stride hs; y2 compact)
__global__ void apply2_kernel(const float* __restrict__ y2, const float* __restrict__ a2,
                              const float* __restrict__ c2, float* __restrict__ h, int hs) {
    int t = blockIdx.x * blockDim.x + threadIdx.x;
    if (t >= N_NODES * D) return;
    int n = t / D, j = t % D;
    h[(size_t)n * hs + j] = fmaxf(y2[t] * a2[j] + c2[j], 0.0f);
}

// ---------------------------------------------------------------------------
extern "C" void kernel_launch(void* const* d_in, const int* in_sizes, int n_in,
                              void* d_out, int out_size, void* d_ws, size_t ws_size,
                              hipStream_t stream) {
    const int*   src        = (const int*)d_in[0];
    const int*   dst        = (const int*)d_in[1];
    const float* node_feats = (const float*)d_in[2];
    const float* edge_feats = (const float*)d_in[3];
    const float* node_W     = (const float*)d_in[4];
    const float* node_b     = (const float*)d_in[5];
    const float* edge_W     = (const float*)d_in[6];
    const float* edge_b     = (const float*)d_in[7];
    const float* epsArr     = (const float*)d_in[8];
    const float* W1         = (const float*)d_in[9];
    const float* b1         = (const float*)d_in[10];
    const float* g1         = (const float*)d_in[11];
    const float* be1        = (const float*)d_in[12];
    const float* W2         = (const float*)d_in[13];
    const float* b2         = (const float*)d_in[14];
    const float* g2         = (const float*)d_in[15];
    const float* be2        = (const float*)d_in[16];
    const float* pred_W     = (const float*)d_in[17];
    const float* pred_b     = (const float*)d_in[18];
    float* out = (float*)d_out;

    float* ws = (float*)d_ws;
    float *h, *tmp, *invd, *st, *aggef;
    int *degi, *off, *cursor, *bsum, *bpre, *adjs, *adje;
    auto layout = [&](int hs, bool with_aggef) -> size_t {
        float* p = ws;
        h = p;    p += (size_t)N_NODES * hs;
        tmp = p;  p += (size_t)N_NODES * D;
        invd = p; p += N_NODES;
        st = p;   p += 768;
        int* ip = (int*)p;
        degi = ip;   ip += N_NODES;
        off = ip;    ip += N_NODES + 1;
        cursor = ip; ip += N_NODES;
        bsum = ip;   ip += NBLK;
        bpre = ip;   ip += NBLK + 1;
        adjs = ip;   ip += N_EDGES;
        adje = ip;   ip += N_EDGES;
        aggef = (float*)ip;
        char* end = (char*)(aggef + (with_aggef ? (size_t)N_NODES * 8 : 0));
        return (size_t)(end - (char*)d_ws);
    };
    int HS = 56, USE_EBASE = 1;
    size_t need = layout(56, true);
    if (ws_size < need) { HS = 50; USE_EBASE = 0; layout(50, false); }

    float* s1 = st, *q1 = st + 128, *s2 = st + 256, *q2 = st + 320;
    float* a1 = st + 384, *c1 = st + 512, *a2 = st + 640, *c2 = st + 704;
    float* y1 = out;   // 40MB in the 44.8MB out buffer; dead before pred writes

    node_enc_kernel<<<(N_NODES + NE_NODES - 1) / NE_NODES, 256, 0, stream>>>(
        node_feats, node_W, node_b, h, HS);

    hipMemsetAsync(degi, 0, N_NODES * sizeof(int), stream);
    k_deg<<<(N_EDGES + 255) / 256, 256, 0, stream>>>(dst, degi);
    k_bsum<<<NBLK, 256, 0, stream>>>(degi, bsum);
    k_bscan<<<1, 512, 0, stream>>>(bsum, bpre);
    k_off<<<NBLK, 256, 0, stream>>>(degi, bpre, off, cursor, invd);
    k_fill<<<(N_EDGES + 255) / 256, 256, 0, stream>>>(src, dst, cursor, adjs, adje);
    if (USE_EBASE)
        k_aggef<<<(N_NODES + 3) / 4, 256, 0, stream>>>(off, adje, edge_feats, aggef);

    for (int layer = 0; layer < 2; layer++) {
        hipMemsetAsync(st, 0, 384 * sizeof(float), stream);
        gather_kernel<<<(N_NODES + 3) / 4, 256, 0, stream>>>(
            off, adjs, adje, aggef, edge_feats, edge_W, edge_b, h, HS,
            invd, epsArr, layer, tmp, USE_EBASE);
        // y1 = hnew @ W1 + b1   (stats s1/q1)
        gemm_tiled<50, 52, 100, 25, 32, false, true><<<625, 256, 0, stream>>>(
            tmp, W1 + layer * D * D2, b1 + layer * D2, st, st, y1, s1, q1, 3125);
        bn_fin_kernel<<<1, 128, 0, stream>>>(s1, q1, g1 + layer * D2, be1 + layer * D2, a1, c1, D2);
        // y2 = relu(bn(y1)) @ W2 + b2   (stats s2/q2)
        gemm_tiled<100, 104, 50, 13, 64, true, true><<<521, 256, 0, stream>>>(
            y1, W2 + layer * D2 * D, b2 + layer * D, a1, c1, tmp, s2, q2, 1563);
        bn_fin_kernel<<<1, 128, 0, stream>>>(s2, q2, g2 + layer * D, be2 + layer * D, a2, c2, D);
        if (layer == 0)
            apply2_kernel<<<(N_NODES * D + 255) / 256, 256, 0, stream>>>(tmp, a2, c2, h, HS);
    }
    // out = relu(bn(y2)) @ pred_W + pred_b   (apply2 fused into staging)
    gemm_tiled<50, 52, 112, 28, 32, true, false><<<625, 256, 0, stream>>>(
        tmp, pred_W, pred_b, a2, c2, out, st, st, 3125);
}

// Round 4
// 900.832 us; speedup vs baseline: 2.8007x; 2.8007x over previous
//
#include <hip/hip_runtime.h>
#include <hip/hip_bf16.h>

#define N_NODES 100000
#define N_EDGES 1600000
#define IN_DIM 8
#define D 50
#define D2 100
#define NTASK 112
#define BN_EPS 1e-5f
#define NBLK ((N_NODES + 255) / 256)   // 391 scan blocks

// ---------------------------------------------------------------------------
// node encoder: h[n,j] = nf[n,:] @ nW + nb   (h row stride = hs)
// ---------------------------------------------------------------------------
#define NE_NODES 40
__global__ __launch_bounds__(256) void node_enc_kernel(
    const float* __restrict__ nf, const float* __restrict__ nW,
    const float* __restrict__ nb, float* __restrict__ h, int hs) {
    __shared__ float sW[IN_DIM * D];
    __shared__ float sb[D];
    __shared__ float snf[NE_NODES * IN_DIM];
    int t = threadIdx.x;
    int n0 = blockIdx.x * NE_NODES;
    for (int i = t; i < IN_DIM * D; i += 256) sW[i] = nW[i];
    for (int i = t; i < D; i += 256) sb[i] = nb[i];
    for (int i = t; i < NE_NODES * IN_DIM; i += 256) {
        int g = n0 * IN_DIM + i;
        snf[i] = (g < N_NODES * IN_DIM) ? nf[g] : 0.0f;
    }
    __syncthreads();
    int j = t % D, grp = t / D;
    if (grp < 5) {
        for (int n = grp * 8; n < grp * 8 + 8; n++) {
            int g = n0 + n;
            if (g >= N_NODES) break;
            float v = sb[j];
#pragma unroll
            for (int k = 0; k < IN_DIM; k++) v += snf[n * IN_DIM + k] * sW[k * D + j];
            h[(size_t)g * hs + j] = v;
        }
    }
}

// ---------------------------------------------------------------------------
// CSR build
// ---------------------------------------------------------------------------
__global__ void k_deg(const int* __restrict__ dst, int* __restrict__ degi) {
    int e = blockIdx.x * blockDim.x + threadIdx.x;
    if (e < N_EDGES) atomicAdd(&degi[dst[e]], 1);
}

__global__ void k_bsum(const int* __restrict__ degi, int* __restrict__ bsum) {
    __shared__ int lds[256];
    int t = threadIdx.x, i = blockIdx.x * 256 + t;
    lds[t] = (i < N_NODES) ? degi[i] : 0;
    __syncthreads();
    for (int s = 128; s > 0; s >>= 1) {
        if (t < s) lds[t] += lds[t + s];
        __syncthreads();
    }
    if (t == 0) bsum[blockIdx.x] = lds[0];
}

__global__ void k_bscan(const int* __restrict__ bsum, int* __restrict__ bpre) {
    __shared__ int lds[512];
    int t = threadIdx.x;
    int x = (t < NBLK) ? bsum[t] : 0;
    lds[t] = x;
    __syncthreads();
    int acc = x;
    for (int s = 1; s < 512; s <<= 1) {
        int add = (t >= s) ? lds[t - s] : 0;
        __syncthreads();
        acc += add;
        lds[t] = acc;
        __syncthreads();
    }
    if (t < NBLK) bpre[t] = acc - x;
}

__global__ void k_off(const int* __restrict__ degi, const int* __restrict__ bpre,
                      int* __restrict__ off, int* __restrict__ cursor,
                      float* __restrict__ invd) {
    __shared__ int lds[256];
    int t = threadIdx.x, i = blockIdx.x * 256 + t;
    int dv = (i < N_NODES) ? degi[i] : 0;
    lds[t] = dv;
    __syncthreads();
    int acc = dv;
    for (int s = 1; s < 256; s <<= 1) {
        int add = (t >= s) ? lds[t - s] : 0;
        __syncthreads();
        acc += add;
        lds[t] = acc;
        __syncthreads();
    }
    int excl = acc - dv + bpre[blockIdx.x];
    if (i < N_NODES) {
        off[i] = excl;
        cursor[i] = excl;
        invd[i] = (dv > 0) ? (1.0f / (float)dv) : 0.0f;
    }
    if (i == 0) off[N_NODES] = N_EDGES;
}

__global__ void k_fill(const int* __restrict__ src, const int* __restrict__ dst,
                       int* __restrict__ cursor, int* __restrict__ adjs,
                       int* __restrict__ adje) {
    int e = blockIdx.x * blockDim.x + threadIdx.x;
    if (e >= N_EDGES) return;
    int d = dst[e];
    int pos = atomicAdd(&cursor[d], 1);
    adjs[pos] = src[e];
    adje[pos] = e;
}

// ---------------------------------------------------------------------------
// aggef[n,k] = sum over incoming edges of ef[e,k]   (once per call)
// ---------------------------------------------------------------------------
__global__ __launch_bounds__(256) void k_aggef(
    const int* __restrict__ off, const int* __restrict__ adje,
    const float* __restrict__ ef, float* __restrict__ aggef) {
    int lane = threadIdx.x & 63, wv = threadIdx.x >> 6;
    int n = blockIdx.x * 4 + wv;
    if (n >= N_NODES) return;
    int p0 = off[n], pend = off[n + 1];
    int g = lane >> 3, k = lane & 7;
    float a = 0.0f;
    for (int q = p0 + g; q < pend; q += 8) {
        int e = adje[q];
        a += ef[(size_t)e * 8 + k];
    }
    a += __shfl_xor(a, 8, 64);
    a += __shfl_xor(a, 16, 64);
    a += __shfl_xor(a, 32, 64);
    if (lane < 8) aggef[(size_t)n * 8 + lane] = a;
}

// ---------------------------------------------------------------------------
// gather + eps-combine. FULL mode (use_ebase): pure h[src] gather, edge-enc
// contribution folded in per-node via aggef @ eW. LEAN mode: R2-style.
// ---------------------------------------------------------------------------
__global__ __launch_bounds__(256) void gather_kernel(
    const int* __restrict__ off, const int* __restrict__ adjs,
    const int* __restrict__ adje, const float* __restrict__ aggef,
    const float* __restrict__ ef, const float* __restrict__ eW,
    const float* __restrict__ eb, const float* __restrict__ h, int hs,
    const float* __restrict__ invd, const float* __restrict__ epsArr, int layer,
    float* __restrict__ hnew, int use_ebase) {
    __shared__ float sW[IN_DIM * D];
    __shared__ float sB[D];
    int t = threadIdx.x;
    for (int i = t; i < IN_DIM * D; i += 256) sW[i] = eW[i];
    for (int i = t; i < D; i += 256) sB[i] = eb[i];
    __syncthreads();
    int lane = t & 63, wv = t >> 6;
    int n = blockIdx.x * 4 + wv;
    if (n >= N_NODES) return;
    int dd = (lane < D) ? lane : (D - 1);
    int p = off[n], pend = off[n + 1];
    int deg = pend - p;
    float acc = 0.0f;
    if (use_ebase) {
        while (p + 4 <= pend) {
            int s0 = adjs[p], s1 = adjs[p + 1], s2 = adjs[p + 2], s3 = adjs[p + 3];
            float h0 = h[(size_t)s0 * hs + dd];
            float h1 = h[(size_t)s1 * hs + dd];
            float h2 = h[(size_t)s2 * hs + dd];
            float h3 = h[(size_t)s3 * hs + dd];
            acc += h0 + h1 + h2 + h3;
            p += 4;
        }
        while (p < pend) { acc += h[(size_t)adjs[p] * hs + dd]; p++; }
    } else {
        const float4* ef4 = (const float4*)ef;
        while (p < pend) {
            int s = adjs[p], e = adje[p];
            float hv = h[(size_t)s * hs + dd];
            float4 f0 = ef4[(size_t)e * 2];
            float4 f1 = ef4[(size_t)e * 2 + 1];
            float ev = sB[dd];
            ev += f0.x * sW[0 * D + dd];
            ev += f0.y * sW[1 * D + dd];
            ev += f0.z * sW[2 * D + dd];
            ev += f0.w * sW[3 * D + dd];
            ev += f1.x * sW[4 * D + dd];
            ev += f1.y * sW[5 * D + dd];
            ev += f1.z * sW[6 * D + dd];
            ev += f1.w * sW[7 * D + dd];
            acc += hv + ev;
            p++;
        }
    }
    if (lane < D) {
        float iv = invd[n];
        float extra = 0.0f;
        if (use_ebase) {
            if (deg > 0) {
                const float* ag = &aggef[(size_t)n * 8];
                float s = 0.0f;
#pragma unroll
                for (int k = 0; k < 8; k++) s += ag[k] * sW[k * D + dd];
                extra = s * iv + sB[dd];
            }
        }
        float epsv = 1.0f + epsArr[layer];
        hnew[(size_t)n * D + lane] = epsv * h[(size_t)n * hs + lane] + iv * acc + extra;
    }
}

// ---------------------------------------------------------------------------
// register-tiled GEMM: Y[N,J] = act(X[N,K]) @ W[K,J] + bias
// NB=32 nodes/tile (100000 % 32 == 0 -> no node guards).
// Thread tile: 4 nodes x NJ columns, JG*NJ == J exactly (no j guards).
// #pragma unroll 2 on K-loop (R3 post-mortem: full unroll -> VGPR 256 + spill).
// KP chosen so KP/4 is odd (LDS phase decorrelation).
// ---------------------------------------------------------------------------
template<int K, int KP, int J, int JG, int NJ, bool BN_IN, bool STATS>
__global__ __launch_bounds__(256, 3) void gemm_tiled(
    const float* __restrict__ X, const float* __restrict__ W,
    const float* __restrict__ bias,
    const float* __restrict__ bna, const float* __restrict__ bnc,
    float* __restrict__ Y, float* __restrict__ sg, float* __restrict__ qg,
    int ntiles) {
    constexpr int NB = 32;
    __shared__ __align__(16) float sh[NB * KP];
    __shared__ __align__(16) float sWT[J * KP];
    __shared__ float sb[J];
    __shared__ float sa[K], sc[K];
    __shared__ float sp[J], qp[J];
    int t = threadIdx.x;
    for (int i = t; i < J * KP; i += 256) {
        int j = i / KP, d = i % KP;
        sWT[i] = (d < K) ? W[d * J + j] : 0.0f;
    }
    for (int i = t; i < J; i += 256) sb[i] = bias[i];
    if (BN_IN) {
        for (int i = t; i < K; i += 256) { sa[i] = bna[i]; sc[i] = bnc[i]; }
    }
    if (STATS) {
        for (int i = t; i < J; i += 256) { sp[i] = 0.0f; qp[i] = 0.0f; }
    }
    int jg = t % JG, ng = t / JG;
    bool active = (ng < NB / 4);
    int nn0 = ng * 4;
    float sacc[NJ], qacc[NJ];
#pragma unroll
    for (int jj = 0; jj < NJ; jj++) { sacc[jj] = 0.0f; qacc[jj] = 0.0f; }
    for (int tile = blockIdx.x; tile < ntiles; tile += gridDim.x) {
        __syncthreads();   // sh reuse across tiles; also orders first sh use after sWT stage
        int base = tile * NB;
        for (int i = t; i < NB * KP; i += 256) {
            int n = i / KP, dp = i % KP;
            float v = 0.0f;
            if (dp < K) {
                v = X[(size_t)(base + n) * K + dp];
                if (BN_IN) v = fmaxf(v * sa[dp] + sc[dp], 0.0f);
            }
            sh[i] = v;
        }
        __syncthreads();
        if (active) {
            float acc[4][NJ];
#pragma unroll
            for (int i = 0; i < 4; i++)
#pragma unroll
                for (int jj = 0; jj < NJ; jj++) acc[i][jj] = sb[jg + jj * JG];
#pragma unroll 2
            for (int d4 = 0; d4 < KP / 4; d4++) {
                float4 av[4], bv[NJ];
#pragma unroll
                for (int i = 0; i < 4; i++)
                    av[i] = *(const float4*)&sh[(nn0 + i) * KP + d4 * 4];
#pragma unroll
                for (int jj = 0; jj < NJ; jj++)
                    bv[jj] = *(const float4*)&sWT[(jg + jj * JG) * KP + d4 * 4];
#pragma unroll
                for (int i = 0; i < 4; i++)
#pragma unroll
                    for (int jj = 0; jj < NJ; jj++) {
                        acc[i][jj] += av[i].x * bv[jj].x;
                        acc[i][jj] += av[i].y * bv[jj].y;
                        acc[i][jj] += av[i].z * bv[jj].z;
                        acc[i][jj] += av[i].w * bv[jj].w;
                    }
            }
#pragma unroll
            for (int i = 0; i < 4; i++) {
                int gn = base + nn0 + i;
#pragma unroll
                for (int jj = 0; jj < NJ; jj++) {
                    float v = acc[i][jj];
                    Y[(size_t)gn * J + jg + jj * JG] = v;
                    if (STATS) { sacc[jj] += v; qacc[jj] += v * v; }
                }
            }
        }
    }
    if (STATS) {
        __syncthreads();
        if (active) {
#pragma unroll
            for (int jj = 0; jj < NJ; jj++) {
                atomicAdd(&sp[jg + jj * JG], sacc[jj]);
                atomicAdd(&qp[jg + jj * JG], qacc[jj]);
            }
        }
        __syncthreads();
        for (int i = t; i < J; i += 256) {
            atomicAdd(&sg[i], sp[i]);
            atomicAdd(&qg[i], qp[i]);
        }
    }
}

// a = gamma*rsqrt(var+eps); c = beta - mu*a
__global__ void bn_fin_kernel(const float* __restrict__ s, const float* __restrict__ q,
                              const float* __restrict__ gamma, const float* __restrict__ beta,
                              float* __restrict__ a, float* __restrict__ c, int dim) {
    int j = threadIdx.x;
    if (j >= dim) return;
    float inv_n = 1.0f / (float)N_NODES;
    float mu = s[j] * inv_n;
    float var = q[j] * inv_n - mu * mu;
    float rs = rsqrtf(var + BN_EPS);
    float av = gamma[j] * rs;
    a[j] = av;
    c[j] = beta[j] - mu * av;
}

// h = relu(y2*a2+c2)  (h row stride hs; y2 compact)
__global__ void apply2_kernel(const float* __restrict__ y2, const float* __restrict__ a2,
                              const float* __restrict__ c2, float* __restrict__ h, int hs) {
    int t = blockIdx.x * blockDim.x + threadIdx.x;
    if (t >= N_NODES * D) return;
    int n = t / D, j = t % D;
    h[(size_t)n * hs + j] = fmaxf(y2[t] * a2[j] + c2[j], 0.0f);
}

// ---------------------------------------------------------------------------
extern "C" void kernel_launch(void* const* d_in, const int* in_sizes, int n_in,
                              void* d_out, int out_size, void* d_ws, size_t ws_size,
                              hipStream_t stream) {
    const int*   src        = (const int*)d_in[0];
    const int*   dst        = (const int*)d_in[1];
    const float* node_feats = (const float*)d_in[2];
    const float* edge_feats = (const float*)d_in[3];
    const float* node_W     = (const float*)d_in[4];
    const float* node_b     = (const float*)d_in[5];
    const float* edge_W     = (const float*)d_in[6];
    const float* edge_b     = (const float*)d_in[7];
    const float* epsArr     = (const float*)d_in[8];
    const float* W1         = (const float*)d_in[9];
    const float* b1         = (const float*)d_in[10];
    const float* g1         = (const float*)d_in[11];
    const float* be1        = (const float*)d_in[12];
    const float* W2         = (const float*)d_in[13];
    const float* b2         = (const float*)d_in[14];
    const float* g2         = (const float*)d_in[15];
    const float* be2        = (const float*)d_in[16];
    const float* pred_W     = (const float*)d_in[17];
    const float* pred_b     = (const float*)d_in[18];
    float* out = (float*)d_out;

    float* ws = (float*)d_ws;
    float *h, *tmp, *invd, *st, *aggef;
    int *degi, *off, *cursor, *bsum, *bpre, *adjs, *adje;
    auto layout = [&](int hs, bool with_aggef) -> size_t {
        float* p = ws;
        h = p;    p += (size_t)N_NODES * hs;
        tmp = p;  p += (size_t)N_NODES * D;
        invd = p; p += N_NODES;
        st = p;   p += 768;
        int* ip = (int*)p;
        degi = ip;   ip += N_NODES;
        off = ip;    ip += N_NODES + 1;
        cursor = ip; ip += N_NODES;
        bsum = ip;   ip += NBLK;
        bpre = ip;   ip += NBLK + 1;
        adjs = ip;   ip += N_EDGES;
        adje = ip;   ip += N_EDGES;
        aggef = (float*)ip;
        char* end = (char*)(aggef + (with_aggef ? (size_t)N_NODES * 8 : 0));
        return (size_t)(end - (char*)d_ws);
    };
    int HS = 56, USE_EBASE = 1;
    size_t need = layout(56, true);
    if (ws_size < need) { HS = 50; USE_EBASE = 0; layout(50, false); }

    float* s1 = st, *q1 = st + 128, *s2 = st + 256, *q2 = st + 320;
    float* a1 = st + 384, *c1 = st + 512, *a2 = st + 640, *c2 = st + 704;
    float* y1 = out;   // 40MB in the 44.8MB out buffer; dead before pred writes

    node_enc_kernel<<<(N_NODES + NE_NODES - 1) / NE_NODES, 256, 0, stream>>>(
        node_feats, node_W, node_b, h, HS);

    hipMemsetAsync(degi, 0, N_NODES * sizeof(int), stream);
    k_deg<<<(N_EDGES + 255) / 256, 256, 0, stream>>>(dst, degi);
    k_bsum<<<NBLK, 256, 0, stream>>>(degi, bsum);
    k_bscan<<<1, 512, 0, stream>>>(bsum, bpre);
    k_off<<<NBLK, 256, 0, stream>>>(degi, bpre, off, cursor, invd);
    k_fill<<<(N_EDGES + 255) / 256, 256, 0, stream>>>(src, dst, cursor, adjs, adje);
    if (USE_EBASE)
        k_aggef<<<(N_NODES + 3) / 4, 256, 0, stream>>>(off, adje, edge_feats, aggef);

    const int GEMM_GRID = 1040;
    for (int layer = 0; layer < 2; layer++) {
        hipMemsetAsync(st, 0, 384 * sizeof(float), stream);
        gather_kernel<<<(N_NODES + 3) / 4, 256, 0, stream>>>(
            off, adjs, adje, aggef, edge_feats, edge_W, edge_b, h, HS,
            invd, epsArr, layer, tmp, USE_EBASE);
        // y1 = hnew @ W1 + b1   (stats s1/q1)
        gemm_tiled<50, 52, 100, 25, 4, false, true><<<GEMM_GRID, 256, 0, stream>>>(
            tmp, W1 + layer * D * D2, b1 + layer * D2, st, st, y1, s1, q1, 3125);
        bn_fin_kernel<<<1, 128, 0, stream>>>(s1, q1, g1 + layer * D2, be1 + layer * D2, a1, c1, D2);
        // y2 = relu(bn(y1)) @ W2 + b2   (stats s2/q2)
        gemm_tiled<100, 108, 50, 25, 2, true, true><<<GEMM_GRID, 256, 0, stream>>>(
            y1, W2 + layer * D2 * D, b2 + layer * D, a1, c1, tmp, s2, q2, 3125);
        bn_fin_kernel<<<1, 128, 0, stream>>>(s2, q2, g2 + layer * D, be2 + layer * D, a2, c2, D);
        if (layer == 0)
            apply2_kernel<<<(N_NODES * D + 255) / 256, 256, 0, stream>>>(tmp, a2, c2, h, HS);
    }
    // out = relu(bn(y2)) @ pred_W + pred_b   (apply2 fused into staging)
    gemm_tiled<50, 52, 112, 28, 4, true, false><<<GEMM_GRID, 256, 0, stream>>>(
        tmp, pred_W, pred_b, a2, c2, out, st, st, 3125);
}